// Round 1
// baseline (25609.790 us; speedup 1.0000x reference)
//
#include <hip/hip_runtime.h>
#include <math.h>

#define Bsz 32
#define Ssz 512
#define Dsz 1024
#define Hsz 1024

// One kernel per (timestep, layer).
// Wave decomposition: global wave id w in [0, 4096):
//   h  = w & 1023  -> output hidden index
//   bg = w >> 10   -> batch group (8 batches)
// Each wave: 4 gate rows (f,i,g,o) of Wx and Wh dotted against inp/hprev for
// 8 batches, K=1024 split across 64 lanes, butterfly allreduce, lanes 0..7 do
// the pointwise update for their batch.
__global__ __launch_bounds__(256) void lstm_step(
    const float* __restrict__ inp, long long inp_stride,
    const float* __restrict__ Wx, const float* __restrict__ Wh,
    const float* __restrict__ bx, const float* __restrict__ bh,
    const float* __restrict__ hprev, float* __restrict__ hnew,
    float* __restrict__ c, float* __restrict__ out)
{
    const int K = 1024;
    int wid  = (blockIdx.x << 2) | (threadIdx.x >> 6);
    int lane = threadIdx.x & 63;
    int h  = wid & (Hsz - 1);
    int bg = wid >> 10;            // 0..3

    const float* wx0 = Wx + (size_t)h * K;
    const float* wx1 = wx0 + (size_t)Hsz * K;
    const float* wx2 = wx1 + (size_t)Hsz * K;
    const float* wx3 = wx2 + (size_t)Hsz * K;
    const float* wh0 = Wh + (size_t)h * K;
    const float* wh1 = wh0 + (size_t)Hsz * K;
    const float* wh2 = wh1 + (size_t)Hsz * K;
    const float* wh3 = wh2 + (size_t)Hsz * K;
    const float* ib  = inp   + (size_t)(bg * 8) * inp_stride;
    const float* hb  = hprev + (size_t)(bg * 8) * Hsz;

    float acc0[8], acc1[8], acc2[8], acc3[8];
#pragma unroll
    for (int i = 0; i < 8; ++i) { acc0[i] = 0.f; acc1[i] = 0.f; acc2[i] = 0.f; acc3[i] = 0.f; }

    for (int t = lane; t < K; t += 64) {
        float a0 = wx0[t], a1 = wx1[t], a2 = wx2[t], a3 = wx3[t];
        float r0 = wh0[t], r1 = wh1[t], r2 = wh2[t], r3 = wh3[t];
#pragma unroll
        for (int bb = 0; bb < 8; ++bb) {
            float xv = ib[(size_t)bb * inp_stride + t];
            float hv = hb[bb * Hsz + t];
            acc0[bb] = fmaf(a0, xv, fmaf(r0, hv, acc0[bb]));
            acc1[bb] = fmaf(a1, xv, fmaf(r1, hv, acc1[bb]));
            acc2[bb] = fmaf(a2, xv, fmaf(r2, hv, acc2[bb]));
            acc3[bb] = fmaf(a3, xv, fmaf(r3, hv, acc3[bb]));
        }
    }

    // allreduce each of the 32 partial sums across 64 lanes
#pragma unroll
    for (int bb = 0; bb < 8; ++bb) {
#pragma unroll
        for (int m = 32; m; m >>= 1) {
            acc0[bb] += __shfl_xor(acc0[bb], m, 64);
            acc1[bb] += __shfl_xor(acc1[bb], m, 64);
            acc2[bb] += __shfl_xor(acc2[bb], m, 64);
            acc3[bb] += __shfl_xor(acc3[bb], m, 64);
        }
    }

    if (lane < 8) {
        // static select chain (avoids dynamic register-array indexing)
        float vf = 0.f, vi = 0.f, vg = 0.f, vo = 0.f;
#pragma unroll
        for (int bb = 0; bb < 8; ++bb) {
            if (lane == bb) { vf = acc0[bb]; vi = acc1[bb]; vg = acc2[bb]; vo = acc3[bb]; }
        }
        int b = bg * 8 + lane;
        vf += bx[h]           + bh[h];
        vi += bx[Hsz + h]     + bh[Hsz + h];
        vg += bx[2 * Hsz + h] + bh[2 * Hsz + h];
        vo += bx[3 * Hsz + h] + bh[3 * Hsz + h];
        float f  = 1.f / (1.f + __expf(-vf));
        float i_ = 1.f / (1.f + __expf(-vi));
        float g  = tanhf(vg);
        float o  = 1.f / (1.f + __expf(-vo));
        size_t idx = (size_t)b * Hsz + h;
        float cn = f * c[idx] + i_ * g;
        float hn = o * tanhf(cn);
        c[idx]    = cn;
        hnew[idx] = hn;
        if (out) out[(size_t)b * (Ssz * Hsz) + h] = hn;   // out pre-offset by t*H
    }
}

// final states into d_out tail: h_n[L,B,H] then c_n[L,B,H]
__global__ __launch_bounds__(256) void copy_final(
    const float* __restrict__ h0, const float* __restrict__ h1,
    const float* __restrict__ c0, const float* __restrict__ c1,
    float* __restrict__ dst)
{
    int i = blockIdx.x * blockDim.x + threadIdx.x;
    const int N = Bsz * Hsz;
    if (i < N) {
        dst[i]         = h0[i];
        dst[N + i]     = h1[i];
        dst[2 * N + i] = c0[i];
        dst[3 * N + i] = c1[i];
    }
}

extern "C" void kernel_launch(void* const* d_in, const int* in_sizes, int n_in,
                              void* d_out, int out_size, void* d_ws, size_t ws_size,
                              hipStream_t stream) {
    const float* x   = (const float*)d_in[0];
    const float* Wx0 = (const float*)d_in[1];
    const float* Wh0 = (const float*)d_in[2];
    const float* bx0 = (const float*)d_in[3];
    const float* bh0 = (const float*)d_in[4];
    const float* Wx1 = (const float*)d_in[5];
    const float* Wh1 = (const float*)d_in[6];
    const float* bx1 = (const float*)d_in[7];
    const float* bh1 = (const float*)d_in[8];
    float* out = (float*)d_out;
    float* ws  = (float*)d_ws;

    const int BH = Bsz * Hsz; // 32768
    float* h0buf[2] = { ws,          ws + BH     };
    float* h1buf[2] = { ws + 2 * BH, ws + 3 * BH };
    float* c0 = ws + 4 * BH;
    float* c1 = ws + 5 * BH;

    // zero-init h and c state (ws is poisoned 0xAA before every call)
    hipMemsetAsync(d_ws, 0, (size_t)6 * BH * sizeof(float), stream);

    dim3 grid(1024), block(256);
    for (int t = 0; t < Ssz; ++t) {
        int cur = t & 1, nxt = cur ^ 1;
        // layer 0: input x[:, t, :], batch stride S*D
        lstm_step<<<grid, block, 0, stream>>>(
            x + (size_t)t * Dsz, (long long)Ssz * Dsz,
            Wx0, Wh0, bx0, bh0,
            h0buf[cur], h0buf[nxt], c0, (float*)nullptr);
        // layer 1: input = layer0's fresh h, batch stride H; writes outputs[:, t, :]
        lstm_step<<<grid, block, 0, stream>>>(
            h0buf[nxt], (long long)Hsz,
            Wx1, Wh1, bx1, bh1,
            h1buf[cur], h1buf[nxt], c1, out + (size_t)t * Hsz);
    }
    // after t=511, fresh state lives in buffer index 0 (S even)
    copy_final<<<dim3(128), block, 0, stream>>>(
        h0buf[0], h1buf[0], c0, c1, out + (size_t)Bsz * Ssz * Hsz);
}

// Round 2
// 20485.107 us; speedup vs baseline: 1.2502x; 1.2502x over previous
//
#include <hip/hip_runtime.h>
#include <hip/hip_bf16.h>
#include <math.h>

#define Bsz 32
#define Ssz 512
#define Dsz 1024
#define Hsz 1024

typedef __bf16 bf16x8 __attribute__((ext_vector_type(8)));
typedef float  f32x4  __attribute__((ext_vector_type(4)));
typedef float  f32x8  __attribute__((ext_vector_type(8)));

struct Params {
  const float* x;
  const float* Wx0; const float* Wh0; const float* bx0; const float* bh0;
  const float* Wx1; const float* Wh1; const float* bx1; const float* bh1;
  __bf16* whi; __bf16* wlo;   // [2][4096][2048] preconverted (PRECONV path)
  __bf16* hbuf;               // [(layer*2+buf)*2 + hl][32][1024] bf16
  float*  c;                  // [2][32][1024]
  float*  part;               // [2][64][4][2048]
  unsigned* cnt;              // [2][64]
  float*  out;
};

__device__ inline void split8(const f32x8 v, bf16x8& hi, bf16x8& lo) {
#pragma unroll
  for (int j = 0; j < 8; ++j) {
    __bf16 h = (__bf16)v[j];
    hi[j] = h;
    lo[j] = (__bf16)(v[j] - (float)h);
  }
}

__device__ inline float sigf(float x) { return 1.f / (1.f + __expf(-x)); }

// Convert weights fp32 -> bf16 hi/lo, concatenating K: [0,1024)=Wx row, [1024,2048)=Wh row.
__global__ __launch_bounds__(256) void preconv(Params p) {
  size_t idx = ((size_t)blockIdx.x * 256 + threadIdx.x) * 8;  // 2*4096*2048 elems
  int layer = (int)(idx >> 23);
  size_t r  = (idx >> 11) & 4095;
  int k0    = (int)(idx & 2047);
  const float* wx = layer ? p.Wx1 : p.Wx0;
  const float* wh = layer ? p.Wh1 : p.Wh0;
  const float* src = (k0 < 1024) ? wx + r * 1024 + k0 : wh + r * 1024 + (k0 - 1024);
  f32x8 v = *reinterpret_cast<const f32x8*>(src);
  bf16x8 hi, lo; split8(v, hi, lo);
  *reinterpret_cast<bf16x8*>(p.whi + idx) = hi;
  *reinterpret_cast<bf16x8*>(p.wlo + idx) = lo;
}

// Fused pipelined step: blocks [0,256) = layer0 @ tau=t, [256,512) = layer1 @ tau=t-1.
// Per layer: 64 n-groups (16 h, gate-complete = 64 W rows) x 4 K-split blocks.
// Wave w of block covers K sub-slice of 128. Last-arriving K-block does reduction+pointwise.
template<bool PRECONV>
__global__ __launch_bounds__(256, 2) void fused_step(Params p, int t) {
  const int layer = blockIdx.x >> 8;
  const int tau = t - layer;
  if (tau < 0 || tau >= Ssz) return;
  const int g    = (blockIdx.x >> 2) & 63;
  const int ks   = blockIdx.x & 3;
  const int w    = threadIdx.x >> 6;
  const int lane = threadIdx.x & 63;
  const int nl   = lane & 15;
  const int quad = lane >> 4;

  const int kw0   = ks * 512 + w * 128;          // global k base of this wave (0..1920)
  const bool xpart = kw0 < 1024;
  const int kl0   = xpart ? kw0 : kw0 - 1024;    // k within source part

  // ---- A source (X = [inp | hprev], rows = 32 batches) ----
  const float* a32 = nullptr; size_t a32_stride = 0;
  const __bf16 *ahi = nullptr, *alo = nullptr;
  if (layer == 0 && xpart) {
    a32 = p.x + (size_t)tau * Dsz + kl0;         // + b * S*D
    a32_stride = (size_t)Ssz * Dsz;
  } else {
    int srcLayer, srcBuf;
    if (xpart) { srcLayer = 0;     srcBuf = tau & 1; }        // layer1 input = h0@tau
    else       { srcLayer = layer; srcBuf = (tau - 1) & 1; }  // recurrent h@tau-1
    size_t base = ((size_t)(srcLayer * 2 + srcBuf) * 2) * (Bsz * Hsz);
    ahi = p.hbuf + base + kl0;
    alo = p.hbuf + base + (Bsz * Hsz) + kl0;
  }

  // ---- B sources: 4 gate rows per n-index ----
  const __bf16 *bhi[4], *blo[4];
  const float  *b32[4];
  const int rowbase = g * 16 + nl;
#pragma unroll
  for (int gate = 0; gate < 4; ++gate) {
    size_t rowg = (size_t)gate * 1024 + rowbase;
    if (PRECONV) {
      size_t off = ((size_t)layer * 4096 + rowg) * 2048 + kw0;
      bhi[gate] = p.whi + off;
      blo[gate] = p.wlo + off;
    } else {
      const float* wx = layer ? p.Wx1 : p.Wx0;
      const float* wh = layer ? p.Wh1 : p.Wh0;
      b32[gate] = (xpart ? wx : wh) + rowg * 1024 + kl0;
    }
  }

  f32x4 acc[4][2];
#pragma unroll
  for (int gt = 0; gt < 4; ++gt)
#pragma unroll
    for (int mt = 0; mt < 2; ++mt) acc[gt][mt] = (f32x4){0.f, 0.f, 0.f, 0.f};

#pragma unroll
  for (int kk = 0; kk < 4; ++kk) {
    const int ko = kk * 32 + quad * 8;
    bf16x8 Ahi[2], Alo[2];
    if (a32) {
#pragma unroll
      for (int mt = 0; mt < 2; ++mt) {
        f32x8 v = *reinterpret_cast<const f32x8*>(a32 + (size_t)(nl + mt * 16) * a32_stride + ko);
        split8(v, Ahi[mt], Alo[mt]);
      }
    } else {
#pragma unroll
      for (int mt = 0; mt < 2; ++mt) {
        Ahi[mt] = *reinterpret_cast<const bf16x8*>(ahi + (size_t)(nl + mt * 16) * Hsz + ko);
        Alo[mt] = *reinterpret_cast<const bf16x8*>(alo + (size_t)(nl + mt * 16) * Hsz + ko);
      }
    }
#pragma unroll
    for (int gate = 0; gate < 4; ++gate) {
      bf16x8 Bhi, Blo;
      if (PRECONV) {
        Bhi = *reinterpret_cast<const bf16x8*>(bhi[gate] + ko);
        Blo = *reinterpret_cast<const bf16x8*>(blo[gate] + ko);
      } else {
        f32x8 wv = *reinterpret_cast<const f32x8*>(b32[gate] + ko);
        split8(wv, Bhi, Blo);
      }
#pragma unroll
      for (int mt = 0; mt < 2; ++mt) {
        acc[gate][mt] = __builtin_amdgcn_mfma_f32_16x16x32_bf16(Ahi[mt], Bhi, acc[gate][mt], 0, 0, 0);
        acc[gate][mt] = __builtin_amdgcn_mfma_f32_16x16x32_bf16(Ahi[mt], Blo, acc[gate][mt], 0, 0, 0);
        acc[gate][mt] = __builtin_amdgcn_mfma_f32_16x16x32_bf16(Alo[mt], Bhi, acc[gate][mt], 0, 0, 0);
      }
    }
  }

  // ---- block-level reduction across 4 waves ----
  __shared__ float red[4][2048];   // [wave][m*64 + gate*16 + nl]
#pragma unroll
  for (int gate = 0; gate < 4; ++gate)
#pragma unroll
    for (int mt = 0; mt < 2; ++mt)
#pragma unroll
      for (int r = 0; r < 4; ++r) {
        int m = mt * 16 + quad * 4 + r;
        red[w][m * 64 + gate * 16 + nl] = acc[gate][mt][r];
      }
  __syncthreads();

  float* pp = p.part + (((size_t)layer * 64 + g) * 4 + ks) * 2048;
#pragma unroll
  for (int j = 0; j < 8; ++j) {
    int e = threadIdx.x + j * 256;
    float s = red[0][e] + red[1][e] + red[2][e] + red[3][e];
    __hip_atomic_store(&pp[e], s, __ATOMIC_RELAXED, __HIP_MEMORY_SCOPE_AGENT);
  }
  __syncthreads();   // ensure all stores issued+drained before counter bump

  __shared__ unsigned oldv;
  if (threadIdx.x == 0)
    oldv = __hip_atomic_fetch_add(&p.cnt[layer * 64 + g], 1u, __ATOMIC_ACQ_REL, __HIP_MEMORY_SCOPE_AGENT);
  __syncthreads();
  if (oldv != 3u) return;

  // ---- last block: sum K-partials, pointwise, write state ----
  float* gl = &red[0][0];          // reuse LDS
  float* base = p.part + ((size_t)layer * 64 + g) * 4 * 2048;
#pragma unroll
  for (int j = 0; j < 8; ++j) {
    int e = threadIdx.x + j * 256;
    float s = 0.f;
#pragma unroll
    for (int kq = 0; kq < 4; ++kq)
      s += __hip_atomic_load(&base[kq * 2048 + e], __ATOMIC_RELAXED, __HIP_MEMORY_SCOPE_AGENT);
    gl[e] = s;
  }
  __syncthreads();

  const float* bx = layer ? p.bx1 : p.bx0;
  const float* bh = layer ? p.bh1 : p.bh0;
#pragma unroll
  for (int j = 0; j < 2; ++j) {
    int idx = threadIdx.x + j * 256;   // 0..511
    int m   = idx & 31;
    int n2  = idx >> 5;                // 0..15
    int hg  = g * 16 + n2;
    float vf = gl[m * 64 + 0 * 16 + n2] + bx[0 * 1024 + hg] + bh[0 * 1024 + hg];
    float vi = gl[m * 64 + 1 * 16 + n2] + bx[1 * 1024 + hg] + bh[1 * 1024 + hg];
    float vg = gl[m * 64 + 2 * 16 + n2] + bx[2 * 1024 + hg] + bh[2 * 1024 + hg];
    float vo = gl[m * 64 + 3 * 16 + n2] + bx[3 * 1024 + hg] + bh[3 * 1024 + hg];
    size_t ci = (size_t)layer * (Bsz * Hsz) + (size_t)m * Hsz + hg;
    float cn = sigf(vf) * p.c[ci] + sigf(vi) * tanhf(vg);
    float hn = sigf(vo) * tanhf(cn);
    p.c[ci] = cn;
    size_t hb = ((size_t)(layer * 2 + (tau & 1)) * 2) * (Bsz * Hsz) + (size_t)m * Hsz + hg;
    __bf16 hh = (__bf16)hn;
    p.hbuf[hb] = hh;
    p.hbuf[hb + Bsz * Hsz] = (__bf16)(hn - (float)hh);
    if (layer == 1)
      p.out[(size_t)m * (Ssz * Hsz) + (size_t)tau * Hsz + hg] = hn;
  }
  if (threadIdx.x == 0)
    __hip_atomic_store(&p.cnt[layer * 64 + g], 0u, __ATOMIC_RELAXED, __HIP_MEMORY_SCOPE_AGENT);
}

// d_out tail: h_n [2,32,1024] then c_n [2,32,1024]; final h in buf 1 (S-1 = 511 odd)
__global__ __launch_bounds__(256) void copy_final(Params p, float* dst) {
  int i = blockIdx.x * 256 + threadIdx.x;   // 0..32767
  const int N = Bsz * Hsz;
  dst[i]         = (float)p.hbuf[2 * N + i] + (float)p.hbuf[3 * N + i];
  dst[N + i]     = (float)p.hbuf[6 * N + i] + (float)p.hbuf[7 * N + i];
  dst[2 * N + i] = p.c[i];
  dst[3 * N + i] = p.c[N + i];
}

extern "C" void kernel_launch(void* const* d_in, const int* in_sizes, int n_in,
                              void* d_out, int out_size, void* d_ws, size_t ws_size,
                              hipStream_t stream) {
  char* ws = (char*)d_ws;
  // layout (bytes)
  const size_t off_h    = 0;                     // 2*2*2*32768 bf16 = 512KB
  const size_t off_c    = 524288;                // 2*32768 f32 = 256KB
  const size_t off_cnt  = 786432;                // 128 u32
  const size_t off_part = 790528;                // 2*64*4*2048 f32 = 4MB
  const size_t off_whi  = 4984832;               // 2*4096*2048 bf16 = 32MB
  const size_t off_wlo  = off_whi + 33554432;
  const size_t WS_PRE   = off_wlo + 33554432;    // ~68.8MB

  Params p;
  p.x   = (const float*)d_in[0];
  p.Wx0 = (const float*)d_in[1]; p.Wh0 = (const float*)d_in[2];
  p.bx0 = (const float*)d_in[3]; p.bh0 = (const float*)d_in[4];
  p.Wx1 = (const float*)d_in[5]; p.Wh1 = (const float*)d_in[6];
  p.bx1 = (const float*)d_in[7]; p.bh1 = (const float*)d_in[8];
  p.whi  = (__bf16*)(ws + off_whi);
  p.wlo  = (__bf16*)(ws + off_wlo);
  p.hbuf = (__bf16*)(ws + off_h);
  p.c    = (float*)(ws + off_c);
  p.part = (float*)(ws + off_part);
  p.cnt  = (unsigned*)(ws + off_cnt);
  p.out  = (float*)d_out;

  // zero h state, c state, counters
  hipMemsetAsync(d_ws, 0, off_part, stream);

  const bool pre = ws_size >= WS_PRE;
  if (pre) preconv<<<dim3(8192), dim3(256), 0, stream>>>(p);

  for (int t = 0; t <= Ssz; ++t) {
    if (pre) fused_step<true ><<<dim3(512), dim3(256), 0, stream>>>(p, t);
    else     fused_step<false><<<dim3(512), dim3(256), 0, stream>>>(p, t);
  }
  copy_final<<<dim3(128), dim3(256), 0, stream>>>(p, (float*)d_out + (size_t)Bsz * Ssz * Hsz);
}

// Round 3
// 15112.137 us; speedup vs baseline: 1.6947x; 1.3555x over previous
//
#include <hip/hip_runtime.h>
#include <math.h>

#define Bsz 32
#define Ssz 512
#define Hsz 1024

typedef _Float16 f16x8 __attribute__((ext_vector_type(8)));
typedef float    f32x4 __attribute__((ext_vector_type(4)));
typedef float    f32x8 __attribute__((ext_vector_type(8)));

struct P {
  const float *x, *Wx0, *Wh0, *bx0, *bh0, *Wx1, *Wh1, *bx1, *bh1;
  _Float16 *h0hi, *h0lo;   // ring[8][32][1024]
  _Float16 *h1hi, *h1lo;   // ring[2][32][1024]
  _Float16 *wsw;           // swizzled fp16 weights [2][64 blk][64 ks][4 m][64 lane][8]
  unsigned *cnt0, *cnt1;   // [512] stage completion counters
  float *out;
};

// fp32 weights -> fp16, swizzled to exact MFMA A-frag order.
// idx bits: lane[0:5] m[6:7] ks[8:13] blk[14:19] layer[20]
__global__ __launch_bounds__(256) void preconv(P p) {
  unsigned idx   = blockIdx.x * 256 + threadIdx.x;        // < 2^21
  unsigned lane  = idx & 63;
  unsigned m     = (idx >> 6) & 3;
  unsigned ks    = (idx >> 8) & 63;
  unsigned blk   = (idx >> 14) & 63;
  unsigned layer = idx >> 20;
  unsigned hidx  = blk * 16 + (lane & 15);
  unsigned k     = ks * 32 + (lane >> 4) * 8;
  unsigned row   = m * 1024 + hidx;
  const float* src;
  if (layer == 0) src = (k < 1024) ? p.Wx0 + (size_t)row * 1024 + k
                                   : p.Wh0 + (size_t)row * 1024 + (k - 1024);
  else            src = (k < 1024) ? p.Wx1 + (size_t)row * 1024 + k
                                   : p.Wh1 + (size_t)row * 1024 + (k - 1024);
  f32x8 v = *reinterpret_cast<const f32x8*>(src);
  f16x8 h;
#pragma unroll
  for (int j = 0; j < 8; ++j) h[j] = (_Float16)v[j];
  *reinterpret_cast<f16x8*>(p.wsw + (size_t)idx * 8) = h;
}

// Persistent pipelined LSTM. 128 blocks x 512 thr.
// blk 0..63: layer0 (K = [x | h0prev]); blk 64..127: layer1 (K = [h0(s) | h1prev]).
// Block owns h-indices hb*16..hb*16+15, all 4 gates.
__global__ __launch_bounds__(512, 2) void lstm_persist(P p) {
  const int blk   = blockIdx.x;
  const int layer = blk >> 6;
  const int hb    = blk & 63;
  const int tid   = threadIdx.x;
  const int w     = tid >> 6;
  const int lane  = tid & 63;
  const int nl    = lane & 15;
  const int quad  = lane >> 4;

  __shared__ float red[4][64 * 33];   // 33.8KB reduce slabs
  __shared__ float csl[Bsz * 16];     // c state [b][hl]
  __shared__ float bsum[64];          // bx+bh  [gate*16+hl]

  if (tid < 64) {
    int r = (tid >> 4) * 1024 + hb * 16 + (tid & 15);
    bsum[tid] = layer ? (p.bx1[r] + p.bh1[r]) : (p.bx0[r] + p.bh0[r]);
  }
  csl[tid] = 0.f;
  __syncthreads();

  const _Float16* wslab = p.wsw + (size_t)(layer * 64 + hb) * 131072;
  const bool xwave = (layer == 0) && (w < 4);
  const int  kloc  = (w & 3) * 256;            // k offset within 1024-part

  for (int s = 0; s < Ssz; ++s) {
    if (tid == 0) {
      if (layer == 0) {
        if (s > 0)
          while (__hip_atomic_load(p.cnt0 + (s - 1), __ATOMIC_ACQUIRE, __HIP_MEMORY_SCOPE_AGENT) < 64) {}
        if (s >= 8)
          while (__hip_atomic_load(p.cnt1 + (s - 8), __ATOMIC_ACQUIRE, __HIP_MEMORY_SCOPE_AGENT) < 64) {}
      } else {
        while (__hip_atomic_load(p.cnt0 + s, __ATOMIC_ACQUIRE, __HIP_MEMORY_SCOPE_AGENT) < 64) {}
        if (s > 0)
          while (__hip_atomic_load(p.cnt1 + (s - 1), __ATOMIC_ACQUIRE, __HIP_MEMORY_SCOPE_AGENT) < 64) {}
      }
    }
    __syncthreads();

    // activation source for this wave's K-slab
    const _Float16 *bhiP = nullptr, *bloP = nullptr;
    if (layer == 0) {
      if (!xwave) {
        int slot = (s - 1) & 7;
        bhiP = p.h0hi + slot * 32768 + kloc;
        bloP = p.h0lo + slot * 32768 + kloc;
      }
    } else {
      if (w < 4) { int slot = s & 7;       bhiP = p.h0hi + slot * 32768 + kloc; bloP = p.h0lo + slot * 32768 + kloc; }
      else       { int slot = (s - 1) & 1; bhiP = p.h1hi + slot * 32768 + kloc; bloP = p.h1lo + slot * 32768 + kloc; }
    }

    f32x4 acc[4][2];
#pragma unroll
    for (int m = 0; m < 4; ++m)
#pragma unroll
      for (int nt = 0; nt < 2; ++nt) acc[m][nt] = (f32x4){0.f, 0.f, 0.f, 0.f};

#pragma unroll 2
    for (int kk = 0; kk < 8; ++kk) {
      f16x8 Bh[2], Bl[2];
      if (xwave) {
#pragma unroll
        for (int nt = 0; nt < 2; ++nt) {
          const float* xp = p.x + ((size_t)(nl + nt * 16) * Ssz + s) * 1024 + kloc + kk * 32 + quad * 8;
          f32x8 v = *reinterpret_cast<const f32x8*>(xp);
#pragma unroll
          for (int j = 0; j < 8; ++j) {
            _Float16 hv = (_Float16)v[j];
            Bh[nt][j] = hv;
            Bl[nt][j] = (_Float16)(v[j] - (float)hv);
          }
        }
      } else {
#pragma unroll
        for (int nt = 0; nt < 2; ++nt) {
          int aoff = (nl + nt * 16) * 1024 + kk * 32 + quad * 8;
          Bh[nt] = *reinterpret_cast<const f16x8*>(bhiP + aoff);
          Bl[nt] = *reinterpret_cast<const f16x8*>(bloP + aoff);
        }
      }
#pragma unroll
      for (int m = 0; m < 4; ++m) {
        f16x8 A = *reinterpret_cast<const f16x8*>(wslab + (size_t)(((w * 8 + kk) * 4 + m) * 64 + lane) * 8);
#pragma unroll
        for (int nt = 0; nt < 2; ++nt) {
          acc[m][nt] = __builtin_amdgcn_mfma_f32_16x16x32_f16(A, Bh[nt], acc[m][nt], 0, 0, 0);
          acc[m][nt] = __builtin_amdgcn_mfma_f32_16x16x32_f16(A, Bl[nt], acc[m][nt], 0, 0, 0);
        }
      }
    }

    // tree-reduce 8 waves -> slab 0.  D layout: row = quad*4+reg (h-local), col = nl (batch)
#define DUMP(sl)                                                            \
    {int _s=(sl); _Pragma("unroll") for (int m = 0; m < 4; ++m)             \
      _Pragma("unroll") for (int nt = 0; nt < 2; ++nt)                      \
        _Pragma("unroll") for (int r = 0; r < 4; ++r)                       \
          red[_s][(m * 16 + quad * 4 + r) * 33 + nt * 16 + nl] = acc[m][nt][r];}
#define GATH(sl)                                                            \
    {int _s=(sl); _Pragma("unroll") for (int m = 0; m < 4; ++m)             \
      _Pragma("unroll") for (int nt = 0; nt < 2; ++nt)                      \
        _Pragma("unroll") for (int r = 0; r < 4; ++r)                       \
          acc[m][nt][r] += red[_s][(m * 16 + quad * 4 + r) * 33 + nt * 16 + nl];}

    if (w >= 4) DUMP(w - 4)
    __syncthreads();
    if (w < 4) GATH(w)
    __syncthreads();
    if (w == 2 || w == 3) DUMP(w - 2)
    __syncthreads();
    if (w < 2) GATH(w)
    __syncthreads();
    if (w == 1) DUMP(0)
    __syncthreads();
    if (w == 0) { GATH(0) DUMP(0) }
    __syncthreads();

    // pointwise: tid -> hl = tid&15, b = tid>>4
    {
      int hl = tid & 15, b = tid >> 4;
      float gf = red[0][(0 * 16 + hl) * 33 + b] + bsum[0 * 16 + hl];
      float gi = red[0][(1 * 16 + hl) * 33 + b] + bsum[1 * 16 + hl];
      float gg = red[0][(2 * 16 + hl) * 33 + b] + bsum[2 * 16 + hl];
      float go = red[0][(3 * 16 + hl) * 33 + b] + bsum[3 * 16 + hl];
      float f  = 1.f / (1.f + __expf(-gf));
      float i  = 1.f / (1.f + __expf(-gi));
      float g  = tanhf(gg);
      float o  = 1.f / (1.f + __expf(-go));
      float c  = f * csl[b * 16 + hl] + i * g;
      float hn = o * tanhf(c);
      csl[b * 16 + hl] = c;
      _Float16 hh = (_Float16)hn;
      _Float16 hl16 = (_Float16)(hn - (float)hh);
      int hg = hb * 16 + hl;
      if (layer == 0) {
        int slot = s & 7;
        p.h0hi[slot * 32768 + b * 1024 + hg] = hh;
        p.h0lo[slot * 32768 + b * 1024 + hg] = hl16;
      } else {
        int slot = s & 1;
        p.h1hi[slot * 32768 + b * 1024 + hg] = hh;
        p.h1lo[slot * 32768 + b * 1024 + hg] = hl16;
        p.out[(size_t)b * (Ssz * Hsz) + (size_t)s * Hsz + hg] = hn;
      }
      if (s == Ssz - 1) {
        float* tail = p.out + (size_t)Bsz * Ssz * Hsz;
        tail[layer * 32768 + b * 1024 + hg] = hn;            // h_n
        tail[65536 + layer * 32768 + b * 1024 + hg] = c;     // c_n
      }
    }
    __syncthreads();   // all stores drained (barrier implies vmcnt(0)) before flag
    if (tid == 0) {
      unsigned* cp = (layer ? p.cnt1 : p.cnt0) + s;
      __hip_atomic_fetch_add(cp, 1u, __ATOMIC_RELEASE, __HIP_MEMORY_SCOPE_AGENT);
    }
  }
}

extern "C" void kernel_launch(void* const* d_in, const int* in_sizes, int n_in,
                              void* d_out, int out_size, void* d_ws, size_t ws_size,
                              hipStream_t stream) {
  char* ws = (char*)d_ws;
  P p;
  p.x   = (const float*)d_in[0];
  p.Wx0 = (const float*)d_in[1]; p.Wh0 = (const float*)d_in[2];
  p.bx0 = (const float*)d_in[3]; p.bh0 = (const float*)d_in[4];
  p.Wx1 = (const float*)d_in[5]; p.Wh1 = (const float*)d_in[6];
  p.bx1 = (const float*)d_in[7]; p.bh1 = (const float*)d_in[8];

  p.h0hi = (_Float16*)(ws);                       // 8*32768*2B = 512KB
  p.h0lo = (_Float16*)(ws + 524288);              // 512KB
  p.h1hi = (_Float16*)(ws + 1048576);             // 128KB
  p.h1lo = (_Float16*)(ws + 1179648);             // 128KB
  p.cnt0 = (unsigned*)(ws + 1310720);             // 2KB
  p.cnt1 = (unsigned*)(ws + 1312768);             // 2KB
  p.wsw  = (_Float16*)(ws + 2097152);             // 32MB
  p.out  = (float*)d_out;

  // zero rings + counters (ws poisoned 0xAA each call)
  hipMemsetAsync(d_ws, 0, 2097152, stream);
  preconv<<<dim3(8192), dim3(256), 0, stream>>>(p);
  lstm_persist<<<dim3(128), dim3(512), 0, stream>>>(p);
}

// Round 4
// 9749.259 us; speedup vs baseline: 2.6268x; 1.5501x over previous
//
#include <hip/hip_runtime.h>
#include <math.h>

#define Bsz 32
#define Ssz 512
#define Hsz 1024

typedef _Float16 f16x8 __attribute__((ext_vector_type(8)));
typedef float    f32x4 __attribute__((ext_vector_type(4)));
typedef float    f32x8 __attribute__((ext_vector_type(8)));

struct P {
  const float *x, *Wx0, *Wh0, *bx0, *bh0, *Wx1, *Wh1, *bx1, *bh1;
  _Float16 *h0hi, *h0lo;   // ring[4][32][1024]
  _Float16 *h1hi, *h1lo;   // ring[2][32][1024]
  unsigned *fl0, *fl1;     // [512][64] flags, 16B stride
  _Float16 *wsw;           // swizzled fp16 weights [2][64 blk][64 ks][4 m][64 lane][8]
  float *out;
};

// fp32 weights -> fp16, swizzled to exact MFMA A-frag order.
// idx bits: lane[0:5] m[6:7] ks[8:13] blk[14:19] layer[20]
__global__ __launch_bounds__(256) void preconv(P p) {
  unsigned idx   = blockIdx.x * 256 + threadIdx.x;        // < 2^21
  unsigned lane  = idx & 63;
  unsigned m     = (idx >> 6) & 3;
  unsigned ks    = (idx >> 8) & 63;
  unsigned blk   = (idx >> 14) & 63;
  unsigned layer = idx >> 20;
  unsigned hidx  = blk * 16 + (lane & 15);
  unsigned k     = ks * 32 + (lane >> 4) * 8;
  unsigned row   = m * 1024 + hidx;
  const float* src;
  if (layer == 0) src = (k < 1024) ? p.Wx0 + (size_t)row * 1024 + k
                                   : p.Wh0 + (size_t)row * 1024 + (k - 1024);
  else            src = (k < 1024) ? p.Wx1 + (size_t)row * 1024 + k
                                   : p.Wh1 + (size_t)row * 1024 + (k - 1024);
  f32x8 v = *reinterpret_cast<const f32x8*>(src);
  f16x8 h;
#pragma unroll
  for (int j = 0; j < 8; ++j) h[j] = (_Float16)v[j];
  *reinterpret_cast<f16x8*>(p.wsw + (size_t)idx * 8) = h;
}

// Persistent pipelined LSTM. 128 blocks x 512 thr, weights resident in VGPRs.
// blk 0..63: layer0 (K = [x | h0prev]); blk 64..127: layer1 (K = [h0(s) | h1prev]).
__global__ __launch_bounds__(512, 2) void lstm_persist(P p) {
  const int blk   = blockIdx.x;
  const int layer = blk >> 6;
  const int hb    = blk & 63;
  const int tid   = threadIdx.x;
  const int w     = tid >> 6;
  const int lane  = tid & 63;
  const int nl    = lane & 15;
  const int quad  = lane >> 4;

  __shared__ float red[4][64 * 33];   // reduce slabs
  __shared__ float csl[Bsz * 16];     // c state [b][hl]
  __shared__ float bsum[64];          // bx+bh  [gate*16+hl]

  if (tid < 64) {
    int r = (tid >> 4) * 1024 + hb * 16 + (tid & 15);
    bsum[tid] = layer ? (p.bx1[r] + p.bh1[r]) : (p.bx0[r] + p.bh0[r]);
  }
  csl[tid] = 0.f;
  __syncthreads();

  // ---- weights: 32 frags = 128 VGPR per lane, loaded once ----
  const _Float16* wslab = p.wsw + (size_t)(layer * 64 + hb) * 131072;
  f16x8 Wr[32];
#pragma unroll
  for (int kk = 0; kk < 8; ++kk)
#pragma unroll
    for (int m = 0; m < 4; ++m)
      Wr[kk * 4 + m] = *reinterpret_cast<const f16x8*>(
          wslab + (size_t)(((w * 8 + kk) * 4 + m) * 64 + lane) * 8);

  const bool xwave = (layer == 0) && (w < 4);
  const int  kloc  = (w & 3) * 256;

  for (int s = 0; s < Ssz; ++s) {
    // ---- stage barrier: wave 0 lanes spin on 64 per-block flags ----
    if (tid < 64) {
      if (layer == 0) {
        if (s > 0)
          while (__hip_atomic_load(p.fl0 + ((s - 1) * 64 + tid) * 4,
                                   __ATOMIC_RELAXED, __HIP_MEMORY_SCOPE_AGENT) == 0u) {}
        if (s >= 4)
          while (__hip_atomic_load(p.fl1 + ((s - 4) * 64 + tid) * 4,
                                   __ATOMIC_RELAXED, __HIP_MEMORY_SCOPE_AGENT) == 0u) {}
      } else {
        while (__hip_atomic_load(p.fl0 + (s * 64 + tid) * 4,
                                 __ATOMIC_RELAXED, __HIP_MEMORY_SCOPE_AGENT) == 0u) {}
        if (s > 0)
          while (__hip_atomic_load(p.fl1 + ((s - 1) * 64 + tid) * 4,
                                   __ATOMIC_RELAXED, __HIP_MEMORY_SCOPE_AGENT) == 0u) {}
      }
      __builtin_amdgcn_fence(__ATOMIC_ACQUIRE, "agent");
    }
    __syncthreads();

    // activation source for this wave's K-slab
    const _Float16 *bhiP = nullptr, *bloP = nullptr;
    if (layer == 0) {
      if (!xwave) {
        int slot = (s - 1) & 3;
        bhiP = p.h0hi + slot * 32768 + kloc;
        bloP = p.h0lo + slot * 32768 + kloc;
      }
    } else {
      if (w < 4) { int slot = s & 3;       bhiP = p.h0hi + slot * 32768 + kloc; bloP = p.h0lo + slot * 32768 + kloc; }
      else       { int slot = (s - 1) & 1; bhiP = p.h1hi + slot * 32768 + kloc; bloP = p.h1lo + slot * 32768 + kloc; }
    }

    f32x4 acc[4][2];
#pragma unroll
    for (int m = 0; m < 4; ++m)
#pragma unroll
      for (int nt = 0; nt < 2; ++nt) acc[m][nt] = (f32x4){0.f, 0.f, 0.f, 0.f};

#pragma unroll
    for (int kk = 0; kk < 8; ++kk) {
      f16x8 Bh[2], Bl[2];
      if (xwave) {
#pragma unroll
        for (int nt = 0; nt < 2; ++nt) {
          const float* xp = p.x + ((size_t)(nl + nt * 16) * Ssz + s) * 1024 + kloc + kk * 32 + quad * 8;
          f32x8 v = *reinterpret_cast<const f32x8*>(xp);
#pragma unroll
          for (int j = 0; j < 8; ++j) {
            _Float16 hv = (_Float16)v[j];
            Bh[nt][j] = hv;
            Bl[nt][j] = (_Float16)(v[j] - (float)hv);
          }
        }
      } else {
#pragma unroll
        for (int nt = 0; nt < 2; ++nt) {
          int aoff = (nl + nt * 16) * 1024 + kk * 32 + quad * 8;
          Bh[nt] = *reinterpret_cast<const f16x8*>(bhiP + aoff);
          Bl[nt] = *reinterpret_cast<const f16x8*>(bloP + aoff);
        }
      }
#pragma unroll
      for (int m = 0; m < 4; ++m) {
        f16x8 A = Wr[kk * 4 + m];
#pragma unroll
        for (int nt = 0; nt < 2; ++nt) {
          acc[m][nt] = __builtin_amdgcn_mfma_f32_16x16x32_f16(A, Bh[nt], acc[m][nt], 0, 0, 0);
          acc[m][nt] = __builtin_amdgcn_mfma_f32_16x16x32_f16(A, Bl[nt], acc[m][nt], 0, 0, 0);
        }
      }
    }

    // tree-reduce 8 waves -> slab 0.  D layout: row = quad*4+reg (h-local), col = nl (batch)
#define DUMP(sl)                                                            \
    {int _s=(sl); _Pragma("unroll") for (int m = 0; m < 4; ++m)             \
      _Pragma("unroll") for (int nt = 0; nt < 2; ++nt)                      \
        _Pragma("unroll") for (int r = 0; r < 4; ++r)                       \
          red[_s][(m * 16 + quad * 4 + r) * 33 + nt * 16 + nl] = acc[m][nt][r];}
#define GATH(sl)                                                            \
    {int _s=(sl); _Pragma("unroll") for (int m = 0; m < 4; ++m)             \
      _Pragma("unroll") for (int nt = 0; nt < 2; ++nt)                      \
        _Pragma("unroll") for (int r = 0; r < 4; ++r)                       \
          acc[m][nt][r] += red[_s][(m * 16 + quad * 4 + r) * 33 + nt * 16 + nl];}

    if (w >= 4) DUMP(w - 4)
    __syncthreads();
    if (w < 4) GATH(w)
    __syncthreads();
    if (w == 2 || w == 3) DUMP(w - 2)
    __syncthreads();
    if (w < 2) GATH(w)
    __syncthreads();
    if (w == 1) DUMP(0)
    __syncthreads();
    if (w == 0) { GATH(0) DUMP(0) }
    __syncthreads();

    // pointwise: tid -> hl = tid&15, b = tid>>4
    {
      int hl = tid & 15, b = tid >> 4;
      float gf = red[0][(0 * 16 + hl) * 33 + b] + bsum[0 * 16 + hl];
      float gi = red[0][(1 * 16 + hl) * 33 + b] + bsum[1 * 16 + hl];
      float gg = red[0][(2 * 16 + hl) * 33 + b] + bsum[2 * 16 + hl];
      float go = red[0][(3 * 16 + hl) * 33 + b] + bsum[3 * 16 + hl];
      float f  = 1.f / (1.f + __expf(-gf));
      float i  = 1.f / (1.f + __expf(-gi));
      float g  = tanhf(gg);
      float o  = 1.f / (1.f + __expf(-go));
      float c  = f * csl[b * 16 + hl] + i * g;
      float hn = o * tanhf(c);
      csl[b * 16 + hl] = c;
      _Float16 hh = (_Float16)hn;
      _Float16 hl16 = (_Float16)(hn - (float)hh);
      int hg = hb * 16 + hl;
      if (layer == 0) {
        int slot = s & 3;
        p.h0hi[slot * 32768 + b * 1024 + hg] = hh;
        p.h0lo[slot * 32768 + b * 1024 + hg] = hl16;
      } else {
        int slot = s & 1;
        p.h1hi[slot * 32768 + b * 1024 + hg] = hh;
        p.h1lo[slot * 32768 + b * 1024 + hg] = hl16;
        p.out[(size_t)b * (Ssz * Hsz) + (size_t)s * Hsz + hg] = hn;
      }
      if (s == Ssz - 1) {
        float* tail = p.out + (size_t)Bsz * Ssz * Hsz;
        tail[layer * 32768 + b * 1024 + hg] = hn;            // h_n
        tail[65536 + layer * 32768 + b * 1024 + hg] = c;     // c_n
      }
    }
    __syncthreads();   // all waves' stores at vmcnt(0) before publish
    if (tid == 0) {
      __builtin_amdgcn_fence(__ATOMIC_RELEASE, "agent");     // wbl2: publish block's stores
      __hip_atomic_store((layer ? p.fl1 : p.fl0) + (s * 64 + hb) * 4, 1u,
                         __ATOMIC_RELAXED, __HIP_MEMORY_SCOPE_AGENT);
    }
  }
}

extern "C" void kernel_launch(void* const* d_in, const int* in_sizes, int n_in,
                              void* d_out, int out_size, void* d_ws, size_t ws_size,
                              hipStream_t stream) {
  char* ws = (char*)d_ws;
  P p;
  p.x   = (const float*)d_in[0];
  p.Wx0 = (const float*)d_in[1]; p.Wh0 = (const float*)d_in[2];
  p.bx0 = (const float*)d_in[3]; p.bh0 = (const float*)d_in[4];
  p.Wx1 = (const float*)d_in[5]; p.Wh1 = (const float*)d_in[6];
  p.bx1 = (const float*)d_in[7]; p.bh1 = (const float*)d_in[8];

  p.h0hi = (_Float16*)(ws);                       // 4*32768*2B = 256KB
  p.h0lo = (_Float16*)(ws + 262144);              // 256KB
  p.h1hi = (_Float16*)(ws + 524288);              // 128KB
  p.h1lo = (_Float16*)(ws + 655360);              // 128KB
  p.fl0  = (unsigned*)(ws + 786432);              // 512KB
  p.fl1  = (unsigned*)(ws + 1310720);             // 512KB
  p.wsw  = (_Float16*)(ws + 1835008);             // 32MB
  p.out  = (float*)d_out;

  // zero rings + flags (ws poisoned 0xAA each call; flags MUST start 0)
  hipMemsetAsync(d_ws, 0, 1835008, stream);
  preconv<<<dim3(8192), dim3(256), 0, stream>>>(p);
  lstm_persist<<<dim3(128), dim3(512), 0, stream>>>(p);
}

// Round 5
// 8713.758 us; speedup vs baseline: 2.9390x; 1.1188x over previous
//
#include <hip/hip_runtime.h>
#include <math.h>

#define Bsz 32
#define Ssz 512
#define Hsz 1024

typedef _Float16 f16x8 __attribute__((ext_vector_type(8)));
typedef float    f32x4 __attribute__((ext_vector_type(4)));
typedef float    f32x8 __attribute__((ext_vector_type(8)));
typedef unsigned u32x4 __attribute__((ext_vector_type(4)));

struct P {
  const float *x, *Wx0, *Wh0, *bx0, *bh0, *Wx1, *Wh1, *bx1, *bh1;
  unsigned *h0r;          // [4][32][1024] packed (hi | lo<<16), device-scope only
  unsigned *h1r;          // [2][32][1024]
  unsigned *cnt0, *cnt1;  // [512] per-stage completion counters (monotonic)
  _Float16 *wsw;          // swizzled fp16 weights [2][64 blk][64 ks][4 m][64 lane][8]
  float *out;
};

// fp32 weights -> fp16, swizzled to exact MFMA A-frag order.
// idx bits: lane[0:5] m[6:7] ks[8:13] blk[14:19] layer[20]
__global__ __launch_bounds__(256) void preconv(P p) {
  unsigned idx   = blockIdx.x * 256 + threadIdx.x;        // < 2^21
  unsigned lane  = idx & 63;
  unsigned m     = (idx >> 6) & 3;
  unsigned ks    = (idx >> 8) & 63;
  unsigned blk   = (idx >> 14) & 63;
  unsigned layer = idx >> 20;
  unsigned hidx  = blk * 16 + (lane & 15);
  unsigned k     = ks * 32 + (lane >> 4) * 8;
  unsigned row   = m * 1024 + hidx;
  const float* src;
  if (layer == 0) src = (k < 1024) ? p.Wx0 + (size_t)row * 1024 + k
                                   : p.Wh0 + (size_t)row * 1024 + (k - 1024);
  else            src = (k < 1024) ? p.Wx1 + (size_t)row * 1024 + k
                                   : p.Wh1 + (size_t)row * 1024 + (k - 1024);
  f32x8 v = *reinterpret_cast<const f32x8*>(src);
  f16x8 h;
#pragma unroll
  for (int j = 0; j < 8; ++j) h[j] = (_Float16)v[j];
  *reinterpret_cast<f16x8*>(p.wsw + (size_t)idx * 8) = h;
}

// device-scope (cache-bypassing) read of 8 packed elements -> hi/lo f16x8 frags
__device__ inline void load_bfrag(const unsigned* rowp, f16x8& Bh, f16x8& Bl) {
  u32x4 hw, lw;
  const unsigned long long* q = (const unsigned long long*)rowp;
#pragma unroll
  for (int j = 0; j < 4; ++j) {
    unsigned long long u = __hip_atomic_load(q + j, __ATOMIC_RELAXED, __HIP_MEMORY_SCOPE_AGENT);
    unsigned a = (unsigned)u, b = (unsigned)(u >> 32);
    hw[j] = (a & 0xffffu) | (b << 16);
    lw[j] = (a >> 16) | (b & 0xffff0000u);
  }
  Bh = __builtin_bit_cast(f16x8, hw);
  Bl = __builtin_bit_cast(f16x8, lw);
}

__device__ inline void load_xfrag(const float* xp, f16x8& Bh, f16x8& Bl) {
  f32x8 v = *reinterpret_cast<const f32x8*>(xp);
#pragma unroll
  for (int j = 0; j < 8; ++j) {
    _Float16 hv = (_Float16)v[j];
    Bh[j] = hv; Bl[j] = (_Float16)(v[j] - (float)hv);
  }
}

// Persistent pipelined LSTM. 128 blocks x 512 thr, weights resident in VGPRs,
// all cross-block traffic via device-scope (LLC) accesses -> no cache fences.
__global__ __launch_bounds__(512, 2) void lstm_persist(P p) {
  const int blk   = blockIdx.x;
  const int layer = blk >> 6;
  const int hb    = blk & 63;
  const int tid   = threadIdx.x;
  const int w     = tid >> 6;
  const int lane  = tid & 63;
  const int nl    = lane & 15;
  const int quad  = lane >> 4;

  __shared__ float red[8][64 * 33];   // 67.6KB: one dump slab per wave
  __shared__ float csl[Bsz * 16];     // c state [b][hl]
  __shared__ float bsum[64];          // bx+bh  [gate*16+hl]

  if (tid < 64) {
    int r = (tid >> 4) * 1024 + hb * 16 + (tid & 15);
    bsum[tid] = layer ? (p.bx1[r] + p.bh1[r]) : (p.bx0[r] + p.bh0[r]);
  }
  csl[tid] = 0.f;
  __syncthreads();

  // ---- weights: 32 frags = 128 regs per lane, loaded once ----
  const _Float16* wslab = p.wsw + (size_t)(layer * 64 + hb) * 131072;
  f16x8 Wr[32];
#pragma unroll
  for (int kk = 0; kk < 8; ++kk)
#pragma unroll
    for (int m = 0; m < 4; ++m)
      Wr[kk * 4 + m] = *reinterpret_cast<const f16x8*>(
          wslab + (size_t)(((w * 8 + kk) * 4 + m) * 64 + lane) * 8);

  const bool xwave = (layer == 0) && (w < 4);
  const int  kloc  = (w & 3) * 256;

  for (int s = 0; s < Ssz; ++s) {
    // ---- stage wait: single lane polls per-stage counters ----
    if (tid == 0) {
      if (layer == 0) {
        if (s > 0)
          while (__hip_atomic_load(p.cnt0 + (s - 1), __ATOMIC_RELAXED, __HIP_MEMORY_SCOPE_AGENT) < 64u) {}
        if (s >= 4)
          while (__hip_atomic_load(p.cnt1 + (s - 4), __ATOMIC_RELAXED, __HIP_MEMORY_SCOPE_AGENT) < 64u) {}
      } else {
        while (__hip_atomic_load(p.cnt0 + s, __ATOMIC_RELAXED, __HIP_MEMORY_SCOPE_AGENT) < 64u) {}
        if (s > 0)
          while (__hip_atomic_load(p.cnt1 + (s - 1), __ATOMIC_RELAXED, __HIP_MEMORY_SCOPE_AGENT) < 64u) {}
      }
    }
    __syncthreads();

    // ---- activation sources for this wave's K-slab ----
    const unsigned* bring = nullptr;
    if (layer == 0) { if (!xwave) bring = p.h0r + ((s - 1) & 3) * 32768 + kloc; }
    else {
      if (w < 4) bring = p.h0r + (s & 3) * 32768 + kloc;
      else       bring = p.h1r + ((s - 1) & 1) * 32768 + kloc;
    }
    const float* xbase = p.x + (size_t)s * 1024 + kloc;   // + row*(Ssz*1024)

    f32x4 acc[4][2];
#pragma unroll
    for (int m = 0; m < 4; ++m)
#pragma unroll
      for (int nt = 0; nt < 2; ++nt) acc[m][nt] = (f32x4){0.f, 0.f, 0.f, 0.f};

    // ---- K loop, B-frags double-buffered to overlap LLC loads with MFMA ----
    f16x8 Bh[2][2], Bl[2][2];
    if (xwave) {
      load_xfrag(xbase + (size_t)nl        * (Ssz * 1024) + quad * 8, Bh[0][0], Bl[0][0]);
      load_xfrag(xbase + (size_t)(nl + 16) * (Ssz * 1024) + quad * 8, Bh[0][1], Bl[0][1]);
    } else {
      load_bfrag(bring + nl * 1024        + quad * 8, Bh[0][0], Bl[0][0]);
      load_bfrag(bring + (nl + 16) * 1024 + quad * 8, Bh[0][1], Bl[0][1]);
    }
#pragma unroll
    for (int kk = 0; kk < 8; ++kk) {
      const int cur = kk & 1, nxt = cur ^ 1;
      if (kk < 7) {
        const int ko = (kk + 1) * 32 + quad * 8;
        if (xwave) {
          load_xfrag(xbase + (size_t)nl        * (Ssz * 1024) + ko, Bh[nxt][0], Bl[nxt][0]);
          load_xfrag(xbase + (size_t)(nl + 16) * (Ssz * 1024) + ko, Bh[nxt][1], Bl[nxt][1]);
        } else {
          load_bfrag(bring + nl * 1024        + ko, Bh[nxt][0], Bl[nxt][0]);
          load_bfrag(bring + (nl + 16) * 1024 + ko, Bh[nxt][1], Bl[nxt][1]);
        }
      }
#pragma unroll
      for (int m = 0; m < 4; ++m) {
        f16x8 A = Wr[kk * 4 + m];
#pragma unroll
        for (int nt = 0; nt < 2; ++nt) {
          acc[m][nt] = __builtin_amdgcn_mfma_f32_16x16x32_f16(A, Bh[cur][nt], acc[m][nt], 0, 0, 0);
          acc[m][nt] = __builtin_amdgcn_mfma_f32_16x16x32_f16(A, Bl[cur][nt], acc[m][nt], 0, 0, 0);
        }
      }
    }

    // ---- reduce: dump all 8 waves, parallel 8-way sum into slab 0 ----
    // D layout: row quad*4+reg = h-local, col nl = batch
#pragma unroll
    for (int m = 0; m < 4; ++m)
#pragma unroll
      for (int nt = 0; nt < 2; ++nt)
#pragma unroll
        for (int r = 0; r < 4; ++r)
          red[w][(m * 16 + quad * 4 + r) * 33 + nt * 16 + nl] = acc[m][nt][r];
    __syncthreads();
#pragma unroll
    for (int j = 0; j < 4; ++j) {
      int idx = tid + j * 512;
      int ad = (idx >> 5) * 33 + (idx & 31);
      float ssum = red[0][ad] + red[1][ad] + red[2][ad] + red[3][ad]
                 + red[4][ad] + red[5][ad] + red[6][ad] + red[7][ad];
      red[0][ad] = ssum;
    }
    __syncthreads();

    // ---- pointwise: tid -> hl = tid&15, b = tid>>4 ----
    {
      int hl = tid & 15, b = tid >> 4;
      float gf = red[0][(0 * 16 + hl) * 33 + b] + bsum[0 * 16 + hl];
      float gi = red[0][(1 * 16 + hl) * 33 + b] + bsum[1 * 16 + hl];
      float gg = red[0][(2 * 16 + hl) * 33 + b] + bsum[2 * 16 + hl];
      float go = red[0][(3 * 16 + hl) * 33 + b] + bsum[3 * 16 + hl];
      float f  = 1.f / (1.f + __expf(-gf));
      float i  = 1.f / (1.f + __expf(-gi));
      float g  = tanhf(gg);
      float o  = 1.f / (1.f + __expf(-go));
      float c  = f * csl[b * 16 + hl] + i * g;
      float hn = o * tanhf(c);
      csl[b * 16 + hl] = c;
      _Float16 hh  = (_Float16)hn;
      _Float16 hlo = (_Float16)(hn - (float)hh);
      unsigned pk = (unsigned)__builtin_bit_cast(unsigned short, hh)
                  | ((unsigned)__builtin_bit_cast(unsigned short, hlo) << 16);
      int hg = hb * 16 + hl;
      if (layer == 0) {
        __hip_atomic_store(p.h0r + (s & 3) * 32768 + b * 1024 + hg, pk,
                           __ATOMIC_RELAXED, __HIP_MEMORY_SCOPE_AGENT);
      } else {
        __hip_atomic_store(p.h1r + (s & 1) * 32768 + b * 1024 + hg, pk,
                           __ATOMIC_RELAXED, __HIP_MEMORY_SCOPE_AGENT);
        p.out[(size_t)b * (Ssz * Hsz) + (size_t)s * Hsz + hg] = hn;
      }
      if (s == Ssz - 1) {
        float* tail = p.out + (size_t)Bsz * Ssz * Hsz;
        tail[layer * 32768 + b * 1024 + hg] = hn;            // h_n
        tail[65536 + layer * 32768 + b * 1024 + hg] = c;     // c_n
      }
    }
    __syncthreads();   // drains every wave's device-scope stores (vmcnt(0) before barrier)
    if (tid == 0)
      __hip_atomic_fetch_add((layer ? p.cnt1 : p.cnt0) + s, 1u,
                             __ATOMIC_RELAXED, __HIP_MEMORY_SCOPE_AGENT);
  }
}

extern "C" void kernel_launch(void* const* d_in, const int* in_sizes, int n_in,
                              void* d_out, int out_size, void* d_ws, size_t ws_size,
                              hipStream_t stream) {
  char* ws = (char*)d_ws;
  P p;
  p.x   = (const float*)d_in[0];
  p.Wx0 = (const float*)d_in[1]; p.Wh0 = (const float*)d_in[2];
  p.bx0 = (const float*)d_in[3]; p.bh0 = (const float*)d_in[4];
  p.Wx1 = (const float*)d_in[5]; p.Wh1 = (const float*)d_in[6];
  p.bx1 = (const float*)d_in[7]; p.bh1 = (const float*)d_in[8];

  p.h0r  = (unsigned*)(ws);                       // 4*32768*4B = 512KB
  p.h1r  = (unsigned*)(ws + 524288);              // 256KB
  p.cnt0 = (unsigned*)(ws + 786432);              // 2KB
  p.cnt1 = (unsigned*)(ws + 788480);              // 2KB
  p.wsw  = (_Float16*)(ws + 1048576);             // 32MB
  p.out  = (float*)d_out;

  // zero rings + counters (ws poisoned 0xAA each call; counters MUST start 0,
  // ring slot -1 reads must see h=0)
  hipMemsetAsync(d_ws, 0, 1048576, stream);
  preconv<<<dim3(8192), dim3(256), 0, stream>>>(p);
  lstm_persist<<<dim3(128), dim3(512), 0, stream>>>(p);
}